// Round 1
// baseline (5471.424 us; speedup 1.0000x reference)
//
#include <hip/hip_runtime.h>
#include <math.h>

#define BATCH 1024
#define CONFN 64
#define TREAT 2
#define EMB 512
#define TOPKN 8
#define HID 1024
#define NDOCS 200000

#define FS_K 4116       // 20 + 8*512
#define FS_KP 4128      // padded to mult of 16
#define SS_K 4162       // 2 + 64 + 8*512
#define SS_KP 4176

#define DRANGE 1600     // docs per range
#define NRANGE 125      // 125*1600 = 200000
#define NPG 16          // 1024/64 patient groups
#define NCAND (NRANGE*8)  // 1000 candidates per patient
#define RESCORE 32

// ---------------- workspace layout (bytes) ----------------
static constexpr size_t OFF_P32  = 0;
static constexpr size_t OFF_P64  = OFF_P32  + (size_t)BATCH*EMB*4;      // 2 MB
static constexpr size_t OFF_INV32= OFF_P64  + (size_t)BATCH*EMB*8;      // +4 MB
static constexpr size_t OFF_INV64= OFF_INV32+ (size_t)NDOCS*4;
static constexpr size_t OFF_CS   = OFF_INV64+ (size_t)NDOCS*8;
static constexpr size_t OFF_CI   = OFF_CS   + (size_t)BATCH*NCAND*4;
static constexpr size_t OFF_TOPK = OFF_CI   + (size_t)BATCH*NCAND*4;
static constexpr size_t OFF_FS   = OFF_TOPK + (size_t)BATCH*TOPKN*4;
static constexpr size_t OFF_H1   = OFF_FS   + (size_t)BATCH*FS_KP*4;
static constexpr size_t OFF_PT   = OFF_H1   + (size_t)BATCH*HID*4;
static constexpr size_t OFF_SS   = OFF_PT   + (size_t)BATCH*2*4;
static constexpr size_t OFF_H2   = OFF_SS   + (size_t)BATCH*SS_KP*4;
static constexpr size_t OFF_H3   = OFF_H2   + (size_t)BATCH*HID*4;
// total ~61.5 MB

// d_out layout (floats): outcome[1024] | scores[8192] | indices[8192] | pt[2048] | iv[2048]
#define OUT_SCORES 1024
#define OUT_IDX    9216
#define OUT_PT     17408
#define OUT_IV     19456

// ---------------- patient encoder (fp64 for ranking stability) ----------------
__global__ __launch_bounds__(256) void encode_kernel(
    const float* __restrict__ patient, const float* __restrict__ W_enc,
    const float* __restrict__ b_enc, float* __restrict__ P32, double* __restrict__ P64)
{
    __shared__ float xs[66];
    __shared__ double pre[EMB];
    __shared__ double red[256];
    const int t = threadIdx.x, b = blockIdx.x;
    if (t < 66) xs[t] = patient[b*66 + t];
    __syncthreads();
    for (int e = t; e < EMB; e += 256) {
        double s = (double)b_enc[e];
        const float* wr = W_enc + (size_t)e*66;
        for (int i = 0; i < 66; ++i) s += (double)xs[i] * (double)wr[i];
        pre[e] = s;
    }
    __syncthreads();
    double ss = 0.0;
    for (int e = t; e < EMB; e += 256) ss += pre[e]*pre[e];
    red[t] = ss;
    __syncthreads();
    for (int o = 128; o >= 1; o >>= 1) { if (t < o) red[t] += red[t+o]; __syncthreads(); }
    double n = sqrt(red[0]); if (n < 1e-12) n = 1e-12;
    const double inv = 1.0/n;
    for (int e = t; e < EMB; e += 256) {
        double v = pre[e]*inv;
        P64[(size_t)b*EMB + e] = v;
        P32[(size_t)b*EMB + e] = (float)v;
    }
}

// ---------------- corpus row inverse norms (fp64 accumulate) ----------------
__global__ __launch_bounds__(256) void corpus_norms(
    const float* __restrict__ corpus, float* __restrict__ inv32, double* __restrict__ inv64)
{
    const int t = threadIdx.x;
    const int row = blockIdx.x*4 + (t >> 6);
    const int lane = t & 63;
    const float* rp = corpus + (size_t)row*EMB;
    double ss = 0.0;
#pragma unroll
    for (int m = 0; m < 8; ++m) { float v = rp[lane + 64*m]; ss += (double)v*(double)v; }
#pragma unroll
    for (int off = 32; off >= 1; off >>= 1) ss += __shfl_xor(ss, off, 64);
    if (lane == 0) {
        double n = sqrt(ss); if (n < 1e-12) n = 1e-12;
        double iv = 1.0/n;
        inv64[row] = iv;
        inv32[row] = (float)iv;
    }
}

// ---------------- phase 1: fp32 similarity scan + per-range top-8 ----------------
__global__ __launch_bounds__(256) void sim_scan(
    const float* __restrict__ P32, const float* __restrict__ corpus,
    const float* __restrict__ inv32, float* __restrict__ cand_s, int* __restrict__ cand_i)
{
    __shared__ float As[16][68];   // [k][patient]
    __shared__ float Bs[16][68];   // [k][doc]
    __shared__ float Sc[64][65];   // [patient][doc]
    __shared__ float ivb[64];

    const int t  = threadIdx.x;
    const int dr = blockIdx.x;          // doc range 0..124
    const int pg = blockIdx.y;          // patient group 0..15
    const int pbase = pg * 64;
    const int tx = t & 15, ty = t >> 4;
    const int r  = t >> 2, c4 = (t & 3) * 4;

    float bs8[8]; int bi8[8];
#pragma unroll
    for (int q = 0; q < 8; ++q) { bs8[q] = -INFINITY; bi8[q] = 0; }

    for (int tile = 0; tile < DRANGE/64; ++tile) {
        const int doc0 = dr*DRANGE + tile*64;
        float acc[4][4] = {};
        for (int ks = 0; ks < EMB/16; ++ks) {
            const int k0 = ks*16;
            __syncthreads();
            const float4 av = *reinterpret_cast<const float4*>(&P32[(size_t)(pbase + r)*EMB + k0 + c4]);
            const float4 bv = *reinterpret_cast<const float4*>(&corpus[(size_t)(doc0 + r)*EMB + k0 + c4]);
            As[c4+0][r] = av.x; As[c4+1][r] = av.y; As[c4+2][r] = av.z; As[c4+3][r] = av.w;
            Bs[c4+0][r] = bv.x; Bs[c4+1][r] = bv.y; Bs[c4+2][r] = bv.z; Bs[c4+3][r] = bv.w;
            __syncthreads();
#pragma unroll
            for (int kk = 0; kk < 16; ++kk) {
                const float4 a = *reinterpret_cast<const float4*>(&As[kk][ty*4]);
                const float4 b = *reinterpret_cast<const float4*>(&Bs[kk][tx*4]);
                const float ar[4] = {a.x, a.y, a.z, a.w};
                const float br[4] = {b.x, b.y, b.z, b.w};
#pragma unroll
                for (int i = 0; i < 4; ++i)
#pragma unroll
                    for (int j = 0; j < 4; ++j)
                        acc[i][j] += ar[i]*br[j];
            }
        }
        __syncthreads();
#pragma unroll
        for (int i = 0; i < 4; ++i)
#pragma unroll
            for (int j = 0; j < 4; ++j)
                Sc[ty*4+i][tx*4+j] = acc[i][j];
        if (t < 64) ivb[t] = inv32[doc0 + t];
        __syncthreads();
        if (t < 64) {
            for (int d = 0; d < 64; ++d) {
                const float s = Sc[t][d] * ivb[d];
                const int idx = doc0 + d;
                if (s > bs8[7]) {
                    // branch-free sorted insertion (desc; ties keep earlier index first)
#pragma unroll
                    for (int q = 7; q >= 1; --q) {
                        const bool cq = s > bs8[q];
                        const bool cp = s > bs8[q-1];
                        const float ns = cq ? (cp ? bs8[q-1] : s) : bs8[q];
                        const int   ni = cq ? (cp ? bi8[q-1] : idx) : bi8[q];
                        bs8[q] = ns; bi8[q] = ni;
                    }
                    if (s > bs8[0]) { bs8[0] = s; bi8[0] = idx; }
                }
            }
        }
        __syncthreads();
    }
    if (t < 64) {
        const int p = pbase + t;
        const size_t base = ((size_t)p*NRANGE + dr)*8;
#pragma unroll
        for (int q = 0; q < 8; ++q) { cand_s[base+q] = bs8[q]; cand_i[base+q] = bi8[q]; }
    }
}

// ---------------- phase 2: merge candidates, fp64 rescore, exact top-8 ----------------
__global__ __launch_bounds__(256) void select_rescore(
    const float* __restrict__ cand_s, const int* __restrict__ cand_i,
    const double* __restrict__ P64, const float* __restrict__ corpus,
    const double* __restrict__ inv64, float* __restrict__ out, int* __restrict__ topk)
{
    __shared__ float  ls[NCAND];
    __shared__ int    li[NCAND];
    __shared__ int    chosen[RESCORE];
    __shared__ double rs[RESCORE];
    __shared__ float  red_s[4];
    __shared__ int    red_i[4];
    __shared__ int    red_j[4];
    const int t = threadIdx.x, p = blockIdx.x;
    const int lane = t & 63, wid = t >> 6;

    for (int j = t; j < NCAND; j += 256) {
        ls[j] = cand_s[(size_t)p*NCAND + j];
        li[j] = cand_i[(size_t)p*NCAND + j];
    }
    __syncthreads();

    // approx top-32 by iterative argmax (tie: smaller doc index)
    for (int round = 0; round < RESCORE; ++round) {
        float bs = -INFINITY; int bi = 0x7fffffff, bj = -1;
        for (int j = t; j < NCAND; j += 256) {
            const float s = ls[j]; const int i = li[j];
            if (s > bs || (s == bs && i < bi)) { bs = s; bi = i; bj = j; }
        }
#pragma unroll
        for (int off = 32; off >= 1; off >>= 1) {
            const float os = __shfl_xor(bs, off, 64);
            const int   oi = __shfl_xor(bi, off, 64);
            const int   oj = __shfl_xor(bj, off, 64);
            if (os > bs || (os == bs && oi < bi)) { bs = os; bi = oi; bj = oj; }
        }
        if (lane == 0) { red_s[wid] = bs; red_i[wid] = bi; red_j[wid] = bj; }
        __syncthreads();
        if (t == 0) {
            float s0 = red_s[0]; int i0 = red_i[0], j0 = red_j[0];
            for (int w2 = 1; w2 < 4; ++w2)
                if (red_s[w2] > s0 || (red_s[w2] == s0 && red_i[w2] < i0)) {
                    s0 = red_s[w2]; i0 = red_i[w2]; j0 = red_j[w2];
                }
            chosen[round] = i0;
            ls[j0] = -INFINITY;   // mask winner
        }
        __syncthreads();
    }

    // fp64 rescore of 32 candidates
    for (int c = wid; c < RESCORE; c += 4) {
        const int doc = chosen[c];
        double s = 0.0;
#pragma unroll
        for (int m = 0; m < 8; ++m)
            s += P64[(size_t)p*EMB + lane + 64*m] * (double)corpus[(size_t)doc*EMB + lane + 64*m];
#pragma unroll
        for (int off = 32; off >= 1; off >>= 1) s += __shfl_xor(s, off, 64);
        if (lane == 0) rs[c] = s * inv64[doc];
    }
    __syncthreads();

    // exact top-8: desc score, tie -> smaller index (lax.top_k semantics)
    if (t == 0) {
        for (int k = 0; k < TOPKN; ++k) {
            double bsd = -1e300; int bid = 0x7fffffff, bjd = -1;
            for (int j = 0; j < RESCORE; ++j) {
                const double s = rs[j]; const int i = chosen[j];
                if (s > bsd || (s == bsd && i < bid)) { bsd = s; bid = i; bjd = j; }
            }
            out[OUT_SCORES + p*TOPKN + k] = (float)bsd;
            out[OUT_IDX    + p*TOPKN + k] = (float)bid;
            topk[p*TOPKN + k] = bid;
            rs[bjd] = -1e300;
        }
    }
}

// ---------------- build fs_in = [instruments | retrieved_flat | 0-pad] ----------------
__global__ __launch_bounds__(256) void build_fs(
    const float* __restrict__ instr, const float* __restrict__ corpus,
    const int* __restrict__ topk, float* __restrict__ fs_in)
{
    const int p = blockIdx.x, t = threadIdx.x;
    for (int j = t; j < FS_KP; j += 256) {
        float v = 0.f;
        if (j < 20) v = instr[p*20 + j];
        else if (j < 20 + TOPKN*EMB) {
            const int k = j - 20;
            const int doc = topk[p*TOPKN + (k >> 9)];
            v = corpus[(size_t)doc*EMB + (k & 511)];
        }
        fs_in[(size_t)p*FS_KP + j] = v;
    }
}

// ---------------- build ss_in = [pt | confounders | retrieved_flat | 0-pad] ----------------
__global__ __launch_bounds__(256) void build_ss(
    const float* __restrict__ pt, const float* __restrict__ conf,
    const float* __restrict__ fs_in, float* __restrict__ ss_in)
{
    const int p = blockIdx.x, t = threadIdx.x;
    for (int j = t; j < SS_KP; j += 256) {
        float v = 0.f;
        if (j < 2) v = pt[p*2 + j];
        else if (j < 66) v = conf[p*CONFN + (j - 2)];
        else if (j < 66 + TOPKN*EMB) v = fs_in[(size_t)p*FS_KP + 20 + (j - 66)];
        ss_in[(size_t)p*SS_KP + j] = v;
    }
}

// ---------------- generic tiled GEMM: C = act(X @ W^T + bias) ----------------
__global__ __launch_bounds__(256) void gemm_bias_act(
    const float* __restrict__ X, const float* __restrict__ W,
    const float* __restrict__ bias, float* __restrict__ C,
    int x_stride, int k_true, int k_pad, int c_stride, int do_relu)
{
    __shared__ float As[16][68];   // [k][m]
    __shared__ float Bs[16][68];   // [k][n]
    const int t = threadIdx.x;
    const int n0 = blockIdx.x * 64;
    const int m0 = blockIdx.y * 64;
    const int tx = t & 15, ty = t >> 4;
    const int r = t >> 2, c4 = (t & 3) * 4;
    float acc[4][4] = {};
    for (int k0 = 0; k0 < k_pad; k0 += 16) {
        __syncthreads();
        const float4 av = *reinterpret_cast<const float4*>(&X[(size_t)(m0 + r)*x_stride + k0 + c4]);
        As[c4+0][r] = av.x; As[c4+1][r] = av.y; As[c4+2][r] = av.z; As[c4+3][r] = av.w;
#pragma unroll
        for (int cc = 0; cc < 4; ++cc) {
            const int k = k0 + c4 + cc;
            Bs[c4+cc][r] = (k < k_true) ? W[(size_t)(n0 + r)*k_true + k] : 0.f;
        }
        __syncthreads();
#pragma unroll
        for (int kk = 0; kk < 16; ++kk) {
            const float4 a = *reinterpret_cast<const float4*>(&As[kk][ty*4]);
            const float4 b = *reinterpret_cast<const float4*>(&Bs[kk][tx*4]);
            const float ar[4] = {a.x, a.y, a.z, a.w};
            const float br[4] = {b.x, b.y, b.z, b.w};
#pragma unroll
            for (int i = 0; i < 4; ++i)
#pragma unroll
                for (int j = 0; j < 4; ++j)
                    acc[i][j] += ar[i]*br[j];
        }
    }
#pragma unroll
    for (int i = 0; i < 4; ++i) {
        const int m = m0 + ty*4 + i;
#pragma unroll
        for (int j = 0; j < 4; ++j) {
            const int n = n0 + tx*4 + j;
            float v = acc[i][j] + bias[n];
            if (do_relu) v = fmaxf(v, 0.f);
            C[(size_t)m*c_stride + n] = v;
        }
    }
}

// ---------------- predicted treatment: pt = h1 @ W1b^T + b1b ----------------
__global__ __launch_bounds__(256) void pt_kernel(
    const float* __restrict__ h1, const float* __restrict__ W1b,
    const float* __restrict__ b1b, float* __restrict__ pt, float* __restrict__ out)
{
    const int t = threadIdx.x;
    const int w = blockIdx.x*4 + (t >> 6);  // 0..2047
    const int lane = t & 63;
    const int b = w >> 1, tr = w & 1;
    float s = 0.f;
#pragma unroll
    for (int m = 0; m < 16; ++m)
        s += h1[(size_t)b*HID + lane + 64*m] * W1b[tr*HID + lane + 64*m];
#pragma unroll
    for (int off = 32; off >= 1; off >>= 1) s += __shfl_xor(s, off, 64);
    if (lane == 0) {
        const float v = s + b1b[tr];
        pt[b*2 + tr] = v;
        out[OUT_PT + b*2 + tr] = v;
    }
}

// ---------------- outcome = h3 @ W2c^T + b2c ----------------
__global__ __launch_bounds__(256) void outcome_kernel(
    const float* __restrict__ h3, const float* __restrict__ W2c,
    const float* __restrict__ b2c, float* __restrict__ out)
{
    const int t = threadIdx.x;
    const int b = blockIdx.x*4 + (t >> 6);  // 0..1023
    const int lane = t & 63;
    float s = 0.f;
#pragma unroll
    for (int m = 0; m < 8; ++m)
        s += h3[(size_t)b*512 + lane + 64*m] * W2c[lane + 64*m];
#pragma unroll
    for (int off = 32; off >= 1; off >>= 1) s += __shfl_xor(s, off, 64);
    if (lane == 0) out[b] = s + b2c[0];
}

// ---------------- iv_strength = instruments @ W_iv^T + b_iv ----------------
__global__ __launch_bounds__(256) void iv_kernel(
    const float* __restrict__ instr, const float* __restrict__ W_iv,
    const float* __restrict__ b_iv, float* __restrict__ out)
{
    const int gid = blockIdx.x*256 + threadIdx.x;  // 0..2047
    const int b = gid >> 1, tr = gid & 1;
    float s = b_iv[tr];
#pragma unroll
    for (int i = 0; i < 20; ++i) s += instr[b*20 + i] * W_iv[tr*20 + i];
    out[OUT_IV + gid] = s;
}

extern "C" void kernel_launch(void* const* d_in, const int* in_sizes, int n_in,
                              void* d_out, int out_size, void* d_ws, size_t ws_size,
                              hipStream_t stream)
{
    (void)in_sizes; (void)n_in; (void)out_size; (void)ws_size;
    const float* patient = (const float*)d_in[0];
    const float* conf    = (const float*)d_in[1];
    const float* instr   = (const float*)d_in[2];
    const float* corpus  = (const float*)d_in[3];
    const float* W_enc   = (const float*)d_in[4];
    const float* b_enc   = (const float*)d_in[5];
    const float* W1a     = (const float*)d_in[6];
    const float* b1a     = (const float*)d_in[7];
    const float* W1b     = (const float*)d_in[8];
    const float* b1b     = (const float*)d_in[9];
    const float* W2a     = (const float*)d_in[10];
    const float* b2a     = (const float*)d_in[11];
    const float* W2b     = (const float*)d_in[12];
    const float* b2b     = (const float*)d_in[13];
    const float* W2c     = (const float*)d_in[14];
    const float* b2c     = (const float*)d_in[15];
    const float* W_iv    = (const float*)d_in[16];
    const float* b_iv    = (const float*)d_in[17];
    float* out = (float*)d_out;
    char* ws = (char*)d_ws;

    float*  P32   = (float*) (ws + OFF_P32);
    double* P64   = (double*)(ws + OFF_P64);
    float*  inv32 = (float*) (ws + OFF_INV32);
    double* inv64 = (double*)(ws + OFF_INV64);
    float*  candS = (float*) (ws + OFF_CS);
    int*    candI = (int*)   (ws + OFF_CI);
    int*    topk  = (int*)   (ws + OFF_TOPK);
    float*  fs_in = (float*) (ws + OFF_FS);
    float*  h1    = (float*) (ws + OFF_H1);
    float*  ptb   = (float*) (ws + OFF_PT);
    float*  ss_in = (float*) (ws + OFF_SS);
    float*  h2    = (float*) (ws + OFF_H2);
    float*  h3    = (float*) (ws + OFF_H3);

    encode_kernel<<<BATCH, 256, 0, stream>>>(patient, W_enc, b_enc, P32, P64);
    corpus_norms<<<NDOCS/4, 256, 0, stream>>>(corpus, inv32, inv64);
    sim_scan<<<dim3(NRANGE, NPG), 256, 0, stream>>>(P32, corpus, inv32, candS, candI);
    select_rescore<<<BATCH, 256, 0, stream>>>(candS, candI, P64, corpus, inv64, out, topk);
    build_fs<<<BATCH, 256, 0, stream>>>(instr, corpus, topk, fs_in);
    gemm_bias_act<<<dim3(16, 16), 256, 0, stream>>>(fs_in, W1a, b1a, h1, FS_KP, FS_K, FS_KP, HID, 1);
    pt_kernel<<<512, 256, 0, stream>>>(h1, W1b, b1b, ptb, out);
    build_ss<<<BATCH, 256, 0, stream>>>(ptb, conf, fs_in, ss_in);
    gemm_bias_act<<<dim3(16, 16), 256, 0, stream>>>(ss_in, W2a, b2a, h2, SS_KP, SS_K, SS_KP, HID, 1);
    gemm_bias_act<<<dim3(8, 16), 256, 0, stream>>>(h2, W2b, b2b, h3, HID, HID, HID, 512, 1);
    outcome_kernel<<<BATCH/4, 256, 0, stream>>>(h3, W2c, b2c, out);
    iv_kernel<<<8, 256, 0, stream>>>(instr, W_iv, b_iv, out);
}

// Round 2
// 2488.955 us; speedup vs baseline: 2.1983x; 2.1983x over previous
//
#include <hip/hip_runtime.h>
#include <math.h>
#include <stdint.h>

#define BATCH 1024
#define CONFN 64
#define TREAT 2
#define EMB 512
#define TOPKN 8
#define HID 1024
#define NDOCS 200000

#define FS_K 4116       // 20 + 8*512
#define FS_KP 4128      // padded to mult of 16
#define SS_K 4162       // 2 + 64 + 8*512
#define SS_KP 4176

// ---- retrieval tiling ----
#define DTILE 128               // docs per MFMA tile
#define RTILES 16               // tiles per range
#define DRANGE (DTILE*RTILES)   // 2048 docs per range
#define NRANGE 98               // 98*2048 = 200704 >= 200000 (tail clamped)
#define NPG 8                   // 1024/128 patient groups
#define NCAND (NRANGE*8)        // 784 candidates per patient
#define RESCORE 32

typedef short bf16x8 __attribute__((ext_vector_type(8)));
typedef float f32x4  __attribute__((ext_vector_type(4)));

// ---------------- workspace layout (bytes) ----------------
static constexpr size_t OFF_PB   = 0;                                     // 1 MB bf16 patients
static constexpr size_t OFF_P64  = OFF_PB   + (size_t)BATCH*EMB*2;
static constexpr size_t OFF_CB   = OFF_P64  + (size_t)BATCH*EMB*8;        // 204.8 MB bf16 corpus
static constexpr size_t OFF_INV32= OFF_CB   + (size_t)NDOCS*EMB*2;
static constexpr size_t OFF_INV64= OFF_INV32+ (size_t)NDOCS*4;
static constexpr size_t OFF_CS   = OFF_INV64+ (size_t)NDOCS*8;
static constexpr size_t OFF_CI   = OFF_CS   + (size_t)BATCH*NCAND*4;
static constexpr size_t OFF_TOPK = OFF_CI   + (size_t)BATCH*NCAND*4;
static constexpr size_t OFF_FS   = OFF_TOPK + (size_t)BATCH*TOPKN*4;
static constexpr size_t OFF_H1   = OFF_FS   + (size_t)BATCH*FS_KP*4;
static constexpr size_t OFF_PT   = OFF_H1   + (size_t)BATCH*HID*4;
static constexpr size_t OFF_SS   = OFF_PT   + (size_t)BATCH*2*4;
static constexpr size_t OFF_H2   = OFF_SS   + (size_t)BATCH*SS_KP*4;
static constexpr size_t OFF_H3   = OFF_H2   + (size_t)BATCH*HID*4;
// total ~260 MB

// d_out layout (floats): outcome[1024] | scores[8192] | indices[8192] | pt[2048] | iv[2048]
#define OUT_SCORES 1024
#define OUT_IDX    9216
#define OUT_PT     17408
#define OUT_IV     19456

__device__ __forceinline__ unsigned short f2bf(float x) {
    unsigned int u = __float_as_uint(x);
    unsigned int r = (u + 0x7fffu + ((u >> 16) & 1u)) >> 16;
    return (unsigned short)r;
}

__device__ __forceinline__ void load_lds16(const void* g, void* l) {
    __builtin_amdgcn_global_load_lds(
        (const __attribute__((address_space(1))) uint32_t*)(uintptr_t)g,
        (__attribute__((address_space(3))) uint32_t*)(uintptr_t)l,
        16, 0, 0);
}

// ---------------- patient encoder (fp64 for ranking stability) + bf16 copy ----------------
__global__ __launch_bounds__(256) void encode_kernel(
    const float* __restrict__ patient, const float* __restrict__ W_enc,
    const float* __restrict__ b_enc, unsigned short* __restrict__ Pb, double* __restrict__ P64)
{
    __shared__ float xs[66];
    __shared__ double pre[EMB];
    __shared__ double red[256];
    const int t = threadIdx.x, b = blockIdx.x;
    if (t < 66) xs[t] = patient[b*66 + t];
    __syncthreads();
    for (int e = t; e < EMB; e += 256) {
        double s = (double)b_enc[e];
        const float* wr = W_enc + (size_t)e*66;
        for (int i = 0; i < 66; ++i) s += (double)xs[i] * (double)wr[i];
        pre[e] = s;
    }
    __syncthreads();
    double ss = 0.0;
    for (int e = t; e < EMB; e += 256) ss += pre[e]*pre[e];
    red[t] = ss;
    __syncthreads();
    for (int o = 128; o >= 1; o >>= 1) { if (t < o) red[t] += red[t+o]; __syncthreads(); }
    double n = sqrt(red[0]); if (n < 1e-12) n = 1e-12;
    const double inv = 1.0/n;
    for (int e = t; e < EMB; e += 256) {
        double v = pre[e]*inv;
        P64[(size_t)b*EMB + e] = v;
        Pb[(size_t)b*EMB + e] = f2bf((float)v);
    }
}

// ---------------- corpus prep: inverse norms (fp64) + bf16 conversion ----------------
__global__ __launch_bounds__(256) void corpus_prep(
    const float* __restrict__ corpus, unsigned short* __restrict__ Cb,
    float* __restrict__ inv32, double* __restrict__ inv64)
{
    const int t = threadIdx.x;
    const int row = blockIdx.x*4 + (t >> 6);
    const int lane = t & 63;
    const float* rp = corpus + (size_t)row*EMB + lane*8;
    const float4 v0 = *reinterpret_cast<const float4*>(rp);
    const float4 v1 = *reinterpret_cast<const float4*>(rp + 4);
    double ss = (double)v0.x*v0.x + (double)v0.y*v0.y + (double)v0.z*v0.z + (double)v0.w*v0.w
              + (double)v1.x*v1.x + (double)v1.y*v1.y + (double)v1.z*v1.z + (double)v1.w*v1.w;
#pragma unroll
    for (int off = 32; off >= 1; off >>= 1) ss += __shfl_xor(ss, off, 64);
    // bf16 pack: 8 ushorts -> uint4 (16B store)
    uint4 pk;
    pk.x = (uint32_t)f2bf(v0.x) | ((uint32_t)f2bf(v0.y) << 16);
    pk.y = (uint32_t)f2bf(v0.z) | ((uint32_t)f2bf(v0.w) << 16);
    pk.z = (uint32_t)f2bf(v1.x) | ((uint32_t)f2bf(v1.y) << 16);
    pk.w = (uint32_t)f2bf(v1.z) | ((uint32_t)f2bf(v1.w) << 16);
    *reinterpret_cast<uint4*>(Cb + (size_t)row*EMB + lane*8) = pk;
    if (lane == 0) {
        double n = sqrt(ss); if (n < 1e-12) n = 1e-12;
        double iv = 1.0/n;
        inv64[row] = iv;
        inv32[row] = (float)iv;
    }
}

// ---------------- phase 1: bf16 MFMA similarity scan + per-range top-8 ----------------
// block: 128 patients x one range (2048 docs), 4 waves, each wave 64p x 64d per tile.
__global__ __launch_bounds__(256, 2) void mfma_scan(
    const unsigned short* __restrict__ Pb, const unsigned short* __restrict__ Cb,
    const float* __restrict__ inv32, float* __restrict__ cand_s, int* __restrict__ cand_i)
{
    // staging: fragment-major, set = (kc*8 + grp), each set = 64 lanes * 8 ushorts
    __shared__ unsigned short stageA[16*512];   // 16 KB
    __shared__ unsigned short stageB[16*512];   // 16 KB
    __shared__ float scs[4*64*17];              // 17.4 KB per-wave score scratch (pad 17)
    __shared__ float ivb[DTILE];
    float* mb_s = scs;                 // overlay after tiles: [128][2][8] scores
    int*   mb_i = (int*)(scs + 2048);  // [128][2][8] indices

    const int t = threadIdx.x;
    const int w = t >> 6, l = t & 63;
    const int lo = l & 15, q = l >> 4;
    const int pg = blockIdx.x;              // 0..7
    const int rg = blockIdx.y;              // 0..97
    const int pbase = pg*128;
    const int wp = (w >> 1)*64, wd = (w & 1)*64;

    float bs8[8]; int bi8[8];
#pragma unroll
    for (int k = 0; k < 8; ++k) { bs8[k] = -INFINITY; bi8[k] = 0; }

    for (int tile = 0; tile < RTILES; ++tile) {
        const int dt0 = rg*DRANGE + tile*DTILE;
        __syncthreads();                                   // ivb/scs safe to rewrite
        if (t < DTILE) { int d = dt0 + t; ivb[t] = inv32[d < NDOCS ? d : 0]; }

        f32x4 acc[4][4];
#pragma unroll
        for (int i = 0; i < 4; ++i)
#pragma unroll
            for (int j = 0; j < 4; ++j) acc[i][j] = (f32x4){0.f, 0.f, 0.f, 0.f};

        for (int kp = 0; kp < 8; ++kp) {
            __syncthreads();                               // stage buffers free
            const int k0 = kp*64;
#pragma unroll
            for (int n = 0; n < 8; ++n) {
                const int s = w*8 + n;                     // 0..31
                const int isA = (s < 16);
                const int ss = isA ? s : s - 16;
                const int kc = ss & 1, grp = ss >> 1;
                const int krd = k0 + kc*32 + q*8;
                if (isA) {
                    const unsigned short* gp = Pb + (size_t)(pbase + 16*grp + lo)*EMB + krd;
                    load_lds16(gp, &stageA[(kc*8 + grp)*512 + l*8]);
                } else {
                    int row = dt0 + 16*grp + lo; if (row >= NDOCS) row = NDOCS - 1;
                    const unsigned short* gp = Cb + (size_t)row*EMB + krd;
                    load_lds16(gp, &stageB[(kc*8 + grp)*512 + l*8]);
                }
            }
            __syncthreads();                               // staging complete
#pragma unroll
            for (int kc = 0; kc < 2; ++kc) {
                bf16x8 af[4], bfr[4];
#pragma unroll
                for (int i = 0; i < 4; ++i)
                    af[i] = *reinterpret_cast<const bf16x8*>(&stageA[(kc*8 + (w>>1)*4 + i)*512 + l*8]);
#pragma unroll
                for (int j = 0; j < 4; ++j)
                    bfr[j] = *reinterpret_cast<const bf16x8*>(&stageB[(kc*8 + (w&1)*4 + j)*512 + l*8]);
#pragma unroll
                for (int i = 0; i < 4; ++i)
#pragma unroll
                    for (int j = 0; j < 4; ++j)
                        acc[i][j] = __builtin_amdgcn_mfma_f32_16x16x32_bf16(af[i], bfr[j], acc[i][j], 0, 0, 0);
            }
        }

        // ---- selection: route each doc-group through per-wave LDS scratch ----
        float* sw = scs + w*64*17;
#pragma unroll
        for (int j = 0; j < 4; ++j) {
#pragma unroll
            for (int i = 0; i < 4; ++i)
#pragma unroll
                for (int r = 0; r < 4; ++r)
                    sw[(16*i + 4*q + r)*17 + lo] = acc[i][j][r];
            // lane l scans patient wp+l over 16 docs (compiler orders via lgkmcnt)
#pragma unroll
            for (int i = 0; i < 16; ++i) {
                const int d = dt0 + wd + 16*j + i;
                const float s = sw[l*17 + i] * ivb[wd + 16*j + i];
                if (d < NDOCS && s > bs8[7]) {
#pragma unroll
                    for (int k = 7; k >= 1; --k) {
                        const bool ck = s > bs8[k];
                        const bool cp = s > bs8[k-1];
                        bs8[k] = ck ? (cp ? bs8[k-1] : s) : bs8[k];
                        bi8[k] = ck ? (cp ? bi8[k-1] : d) : bi8[k];
                    }
                    if (s > bs8[0]) { bs8[0] = s; bi8[0] = d; }
                }
            }
        }
    }

    // ---- merge the two 64-doc halves per patient ----
    __syncthreads();
    {
        const int pl = wp + l, half = w & 1;
#pragma unroll
        for (int k = 0; k < 8; ++k) {
            mb_s[(pl*2 + half)*8 + k] = bs8[k];
            mb_i[(pl*2 + half)*8 + k] = bi8[k];
        }
    }
    __syncthreads();
    if (t < 128) {
        float os8[8]; int oi8[8];
#pragma unroll
        for (int k = 0; k < 8; ++k) { os8[k] = -INFINITY; oi8[k] = 0x7fffffff; }
        for (int u = 0; u < 16; ++u) {
            const float s = mb_s[t*16 + u]; const int idx = mb_i[t*16 + u];
            const bool b7 = (s > os8[7]) || (s == os8[7] && idx < oi8[7]);
            if (b7) {
#pragma unroll
                for (int k = 7; k >= 1; --k) {
                    const bool ck = (s > os8[k])   || (s == os8[k]   && idx < oi8[k]);
                    const bool cp = (s > os8[k-1]) || (s == os8[k-1] && idx < oi8[k-1]);
                    os8[k] = ck ? (cp ? os8[k-1] : s)   : os8[k];
                    oi8[k] = ck ? (cp ? oi8[k-1] : idx) : oi8[k];
                }
                const bool c0 = (s > os8[0]) || (s == os8[0] && idx < oi8[0]);
                if (c0) { os8[0] = s; oi8[0] = idx; }
            }
        }
        const size_t base = (size_t)(pbase + t)*NCAND + rg*8;
#pragma unroll
        for (int k = 0; k < 8; ++k) { cand_s[base + k] = os8[k]; cand_i[base + k] = oi8[k]; }
    }
}

// ---------------- phase 2: merge candidates, fp64 rescore, exact top-8 ----------------
__global__ __launch_bounds__(256) void select_rescore(
    const float* __restrict__ cand_s, const int* __restrict__ cand_i,
    const double* __restrict__ P64, const float* __restrict__ corpus,
    const double* __restrict__ inv64, float* __restrict__ out, int* __restrict__ topk)
{
    __shared__ float  ls[NCAND];
    __shared__ int    li[NCAND];
    __shared__ int    chosen[RESCORE];
    __shared__ double rs[RESCORE];
    __shared__ float  red_s[4];
    __shared__ int    red_i[4];
    __shared__ int    red_j[4];
    const int t = threadIdx.x, p = blockIdx.x;
    const int lane = t & 63, wid = t >> 6;

    for (int j = t; j < NCAND; j += 256) {
        ls[j] = cand_s[(size_t)p*NCAND + j];
        li[j] = cand_i[(size_t)p*NCAND + j];
    }
    __syncthreads();

    for (int round = 0; round < RESCORE; ++round) {
        float bs = -INFINITY; int bi = 0x7fffffff, bj = -1;
        for (int j = t; j < NCAND; j += 256) {
            const float s = ls[j]; const int i = li[j];
            if (s > bs || (s == bs && i < bi)) { bs = s; bi = i; bj = j; }
        }
#pragma unroll
        for (int off = 32; off >= 1; off >>= 1) {
            const float os = __shfl_xor(bs, off, 64);
            const int   oi = __shfl_xor(bi, off, 64);
            const int   oj = __shfl_xor(bj, off, 64);
            if (os > bs || (os == bs && oi < bi)) { bs = os; bi = oi; bj = oj; }
        }
        if (lane == 0) { red_s[wid] = bs; red_i[wid] = bi; red_j[wid] = bj; }
        __syncthreads();
        if (t == 0) {
            float s0 = red_s[0]; int i0 = red_i[0], j0 = red_j[0];
            for (int w2 = 1; w2 < 4; ++w2)
                if (red_s[w2] > s0 || (red_s[w2] == s0 && red_i[w2] < i0)) {
                    s0 = red_s[w2]; i0 = red_i[w2]; j0 = red_j[w2];
                }
            chosen[round] = i0;
            ls[j0] = -INFINITY;
        }
        __syncthreads();
    }

    for (int c = wid; c < RESCORE; c += 4) {
        const int doc = chosen[c];
        double s = 0.0;
#pragma unroll
        for (int m = 0; m < 8; ++m)
            s += P64[(size_t)p*EMB + lane + 64*m] * (double)corpus[(size_t)doc*EMB + lane + 64*m];
#pragma unroll
        for (int off = 32; off >= 1; off >>= 1) s += __shfl_xor(s, off, 64);
        if (lane == 0) rs[c] = s * inv64[doc];
    }
    __syncthreads();

    if (t == 0) {
        for (int k = 0; k < TOPKN; ++k) {
            double bsd = -1e300; int bid = 0x7fffffff, bjd = -1;
            for (int j = 0; j < RESCORE; ++j) {
                const double s = rs[j]; const int i = chosen[j];
                if (s > bsd || (s == bsd && i < bid)) { bsd = s; bid = i; bjd = j; }
            }
            out[OUT_SCORES + p*TOPKN + k] = (float)bsd;
            out[OUT_IDX    + p*TOPKN + k] = (float)bid;
            topk[p*TOPKN + k] = bid;
            rs[bjd] = -1e300;
        }
    }
}

// ---------------- build fs_in = [instruments | retrieved_flat | 0-pad] ----------------
__global__ __launch_bounds__(256) void build_fs(
    const float* __restrict__ instr, const float* __restrict__ corpus,
    const int* __restrict__ topk, float* __restrict__ fs_in)
{
    const int p = blockIdx.x, t = threadIdx.x;
    for (int j = t; j < FS_KP; j += 256) {
        float v = 0.f;
        if (j < 20) v = instr[p*20 + j];
        else if (j < 20 + TOPKN*EMB) {
            const int k = j - 20;
            const int doc = topk[p*TOPKN + (k >> 9)];
            v = corpus[(size_t)doc*EMB + (k & 511)];
        }
        fs_in[(size_t)p*FS_KP + j] = v;
    }
}

__global__ __launch_bounds__(256) void build_ss(
    const float* __restrict__ pt, const float* __restrict__ conf,
    const float* __restrict__ fs_in, float* __restrict__ ss_in)
{
    const int p = blockIdx.x, t = threadIdx.x;
    for (int j = t; j < SS_KP; j += 256) {
        float v = 0.f;
        if (j < 2) v = pt[p*2 + j];
        else if (j < 66) v = conf[p*CONFN + (j - 2)];
        else if (j < 66 + TOPKN*EMB) v = fs_in[(size_t)p*FS_KP + 20 + (j - 66)];
        ss_in[(size_t)p*SS_KP + j] = v;
    }
}

// ---------------- generic tiled GEMM: C = act(X @ W^T + bias) ----------------
__global__ __launch_bounds__(256) void gemm_bias_act(
    const float* __restrict__ X, const float* __restrict__ W,
    const float* __restrict__ bias, float* __restrict__ C,
    int x_stride, int k_true, int k_pad, int c_stride, int do_relu)
{
    __shared__ float As[16][68];
    __shared__ float Bs[16][68];
    const int t = threadIdx.x;
    const int n0 = blockIdx.x * 64;
    const int m0 = blockIdx.y * 64;
    const int tx = t & 15, ty = t >> 4;
    const int r = t >> 2, c4 = (t & 3) * 4;
    float acc[4][4] = {};
    for (int k0 = 0; k0 < k_pad; k0 += 16) {
        __syncthreads();
        const float4 av = *reinterpret_cast<const float4*>(&X[(size_t)(m0 + r)*x_stride + k0 + c4]);
        As[c4+0][r] = av.x; As[c4+1][r] = av.y; As[c4+2][r] = av.z; As[c4+3][r] = av.w;
#pragma unroll
        for (int cc = 0; cc < 4; ++cc) {
            const int k = k0 + c4 + cc;
            Bs[c4+cc][r] = (k < k_true) ? W[(size_t)(n0 + r)*k_true + k] : 0.f;
        }
        __syncthreads();
#pragma unroll
        for (int kk = 0; kk < 16; ++kk) {
            const float4 a = *reinterpret_cast<const float4*>(&As[kk][ty*4]);
            const float4 b = *reinterpret_cast<const float4*>(&Bs[kk][tx*4]);
            const float ar[4] = {a.x, a.y, a.z, a.w};
            const float br[4] = {b.x, b.y, b.z, b.w};
#pragma unroll
            for (int i = 0; i < 4; ++i)
#pragma unroll
                for (int j = 0; j < 4; ++j)
                    acc[i][j] += ar[i]*br[j];
        }
    }
#pragma unroll
    for (int i = 0; i < 4; ++i) {
        const int m = m0 + ty*4 + i;
#pragma unroll
        for (int j = 0; j < 4; ++j) {
            const int n = n0 + tx*4 + j;
            float v = acc[i][j] + bias[n];
            if (do_relu) v = fmaxf(v, 0.f);
            C[(size_t)m*c_stride + n] = v;
        }
    }
}

__global__ __launch_bounds__(256) void pt_kernel(
    const float* __restrict__ h1, const float* __restrict__ W1b,
    const float* __restrict__ b1b, float* __restrict__ pt, float* __restrict__ out)
{
    const int t = threadIdx.x;
    const int w = blockIdx.x*4 + (t >> 6);
    const int lane = t & 63;
    const int b = w >> 1, tr = w & 1;
    float s = 0.f;
#pragma unroll
    for (int m = 0; m < 16; ++m)
        s += h1[(size_t)b*HID + lane + 64*m] * W1b[tr*HID + lane + 64*m];
#pragma unroll
    for (int off = 32; off >= 1; off >>= 1) s += __shfl_xor(s, off, 64);
    if (lane == 0) {
        const float v = s + b1b[tr];
        pt[b*2 + tr] = v;
        out[OUT_PT + b*2 + tr] = v;
    }
}

__global__ __launch_bounds__(256) void outcome_kernel(
    const float* __restrict__ h3, const float* __restrict__ W2c,
    const float* __restrict__ b2c, float* __restrict__ out)
{
    const int t = threadIdx.x;
    const int b = blockIdx.x*4 + (t >> 6);
    const int lane = t & 63;
    float s = 0.f;
#pragma unroll
    for (int m = 0; m < 8; ++m)
        s += h3[(size_t)b*512 + lane + 64*m] * W2c[lane + 64*m];
#pragma unroll
    for (int off = 32; off >= 1; off >>= 1) s += __shfl_xor(s, off, 64);
    if (lane == 0) out[b] = s + b2c[0];
}

__global__ __launch_bounds__(256) void iv_kernel(
    const float* __restrict__ instr, const float* __restrict__ W_iv,
    const float* __restrict__ b_iv, float* __restrict__ out)
{
    const int gid = blockIdx.x*256 + threadIdx.x;
    const int b = gid >> 1, tr = gid & 1;
    float s = b_iv[tr];
#pragma unroll
    for (int i = 0; i < 20; ++i) s += instr[b*20 + i] * W_iv[tr*20 + i];
    out[OUT_IV + gid] = s;
}

extern "C" void kernel_launch(void* const* d_in, const int* in_sizes, int n_in,
                              void* d_out, int out_size, void* d_ws, size_t ws_size,
                              hipStream_t stream)
{
    (void)in_sizes; (void)n_in; (void)out_size; (void)ws_size;
    const float* patient = (const float*)d_in[0];
    const float* conf    = (const float*)d_in[1];
    const float* instr   = (const float*)d_in[2];
    const float* corpus  = (const float*)d_in[3];
    const float* W_enc   = (const float*)d_in[4];
    const float* b_enc   = (const float*)d_in[5];
    const float* W1a     = (const float*)d_in[6];
    const float* b1a     = (const float*)d_in[7];
    const float* W1b     = (const float*)d_in[8];
    const float* b1b     = (const float*)d_in[9];
    const float* W2a     = (const float*)d_in[10];
    const float* b2a     = (const float*)d_in[11];
    const float* W2b     = (const float*)d_in[12];
    const float* b2b     = (const float*)d_in[13];
    const float* W2c     = (const float*)d_in[14];
    const float* b2c     = (const float*)d_in[15];
    const float* W_iv    = (const float*)d_in[16];
    const float* b_iv    = (const float*)d_in[17];
    float* out = (float*)d_out;
    char* ws = (char*)d_ws;

    unsigned short* Pb    = (unsigned short*)(ws + OFF_PB);
    double* P64   = (double*)(ws + OFF_P64);
    unsigned short* Cb    = (unsigned short*)(ws + OFF_CB);
    float*  inv32 = (float*) (ws + OFF_INV32);
    double* inv64 = (double*)(ws + OFF_INV64);
    float*  candS = (float*) (ws + OFF_CS);
    int*    candI = (int*)   (ws + OFF_CI);
    int*    topk  = (int*)   (ws + OFF_TOPK);
    float*  fs_in = (float*) (ws + OFF_FS);
    float*  h1    = (float*) (ws + OFF_H1);
    float*  ptb   = (float*) (ws + OFF_PT);
    float*  ss_in = (float*) (ws + OFF_SS);
    float*  h2    = (float*) (ws + OFF_H2);
    float*  h3    = (float*) (ws + OFF_H3);

    encode_kernel<<<BATCH, 256, 0, stream>>>(patient, W_enc, b_enc, Pb, P64);
    corpus_prep<<<NDOCS/4, 256, 0, stream>>>(corpus, Cb, inv32, inv64);
    mfma_scan<<<dim3(NPG, NRANGE), 256, 0, stream>>>(Pb, Cb, inv32, candS, candI);
    select_rescore<<<BATCH, 256, 0, stream>>>(candS, candI, P64, corpus, inv64, out, topk);
    build_fs<<<BATCH, 256, 0, stream>>>(instr, corpus, topk, fs_in);
    gemm_bias_act<<<dim3(16, 16), 256, 0, stream>>>(fs_in, W1a, b1a, h1, FS_KP, FS_K, FS_KP, HID, 1);
    pt_kernel<<<512, 256, 0, stream>>>(h1, W1b, b1b, ptb, out);
    build_ss<<<BATCH, 256, 0, stream>>>(ptb, conf, fs_in, ss_in);
    gemm_bias_act<<<dim3(16, 16), 256, 0, stream>>>(ss_in, W2a, b2a, h2, SS_KP, SS_K, SS_KP, HID, 1);
    gemm_bias_act<<<dim3(8, 16), 256, 0, stream>>>(h2, W2b, b2b, h3, HID, HID, HID, 512, 1);
    outcome_kernel<<<BATCH/4, 256, 0, stream>>>(h3, W2c, b2c, out);
    iv_kernel<<<8, 256, 0, stream>>>(instr, W_iv, b_iv, out);
}

// Round 3
// 1692.782 us; speedup vs baseline: 3.2322x; 1.4703x over previous
//
#include <hip/hip_runtime.h>
#include <math.h>
#include <stdint.h>

#define BATCH 1024
#define CONFN 64
#define TREAT 2
#define EMB 512
#define TOPKN 8
#define HID 1024
#define NDOCS 200000

#define KP_FS 4224      // padded K for fs (4116) and ss (4162) GEMMs: 33*128
#define R_FS 33         // K rounds for fs/ss gemm

// ---- retrieval tiling ----
#define DTILE 128               // docs per MFMA tile
#define RTILES 16               // tiles per range
#define DRANGE (DTILE*RTILES)   // 2048 docs per range
#define NRANGE 98               // 98*2048 = 200704 >= 200000 (tail clamped)
#define NPG 8                   // 1024/128 patient groups
#define NCAND (NRANGE*8)        // 784 candidates per patient
#define RESCORE 16

typedef short bf16x8 __attribute__((ext_vector_type(8)));
typedef float f32x4  __attribute__((ext_vector_type(4)));

// ---------------- workspace layout (bytes) ----------------
static constexpr size_t OFF_PB   = 0;                                     // bf16 patients
static constexpr size_t OFF_P64  = OFF_PB   + (size_t)BATCH*EMB*2;
static constexpr size_t OFF_CB   = OFF_P64  + (size_t)BATCH*EMB*8;        // bf16 corpus 204.8 MB
static constexpr size_t OFF_INV32= OFF_CB   + (size_t)NDOCS*EMB*2;
static constexpr size_t OFF_INV64= OFF_INV32+ (size_t)NDOCS*4;
static constexpr size_t OFF_CS   = OFF_INV64+ (size_t)NDOCS*8;
static constexpr size_t OFF_CI   = OFF_CS   + (size_t)BATCH*NCAND*4;
static constexpr size_t OFF_TOPK = OFF_CI   + (size_t)BATCH*NCAND*4;
static constexpr size_t OFF_FSB  = OFF_TOPK + (size_t)BATCH*TOPKN*4;      // bf16 [1024][4224]
static constexpr size_t OFF_SSB  = OFF_FSB  + (size_t)BATCH*KP_FS*2;
static constexpr size_t OFF_H1   = OFF_SSB  + (size_t)BATCH*KP_FS*2;      // bf16 [1024][1024]
static constexpr size_t OFF_H2   = OFF_H1   + (size_t)BATCH*HID*2;
static constexpr size_t OFF_H3   = OFF_H2   + (size_t)BATCH*HID*2;        // bf16 [1024][512]
static constexpr size_t OFF_PT   = OFF_H3   + (size_t)BATCH*512*2;
static constexpr size_t OFF_W1   = OFF_PT   + (size_t)BATCH*2*4;          // bf16 W1a padded
static constexpr size_t OFF_W2A  = OFF_W1   + (size_t)HID*KP_FS*2;
static constexpr size_t OFF_W2B  = OFF_W2A  + (size_t)HID*KP_FS*2;        // bf16 [512][1024]
// total ~260 MB

// d_out layout (floats): outcome[1024] | scores[8192] | indices[8192] | pt[2048] | iv[2048]
#define OUT_SCORES 1024
#define OUT_IDX    9216
#define OUT_PT     17408
#define OUT_IV     19456

__device__ __forceinline__ unsigned short f2bf(float x) {
    unsigned int u = __float_as_uint(x);
    unsigned int r = (u + 0x7fffu + ((u >> 16) & 1u)) >> 16;
    return (unsigned short)r;
}
__device__ __forceinline__ float bf2f(unsigned short u) {
    return __uint_as_float(((unsigned int)u) << 16);
}

__device__ __forceinline__ void load_lds16(const void* g, void* l) {
    __builtin_amdgcn_global_load_lds(
        (const __attribute__((address_space(1))) uint32_t*)(uintptr_t)g,
        (__attribute__((address_space(3))) uint32_t*)(uintptr_t)l,
        16, 0, 0);
}

// ---------------- patient encoder (fp64 for ranking stability) + bf16 copy ----------------
__global__ __launch_bounds__(256) void encode_kernel(
    const float* __restrict__ patient, const float* __restrict__ W_enc,
    const float* __restrict__ b_enc, unsigned short* __restrict__ Pb, double* __restrict__ P64)
{
    __shared__ float xs[66];
    __shared__ double pre[EMB];
    __shared__ double red[256];
    const int t = threadIdx.x, b = blockIdx.x;
    if (t < 66) xs[t] = patient[b*66 + t];
    __syncthreads();
    for (int e = t; e < EMB; e += 256) {
        double s = (double)b_enc[e];
        const float* wr = W_enc + (size_t)e*66;
        for (int i = 0; i < 66; ++i) s += (double)xs[i] * (double)wr[i];
        pre[e] = s;
    }
    __syncthreads();
    double ss = 0.0;
    for (int e = t; e < EMB; e += 256) ss += pre[e]*pre[e];
    red[t] = ss;
    __syncthreads();
    for (int o = 128; o >= 1; o >>= 1) { if (t < o) red[t] += red[t+o]; __syncthreads(); }
    double n = sqrt(red[0]); if (n < 1e-12) n = 1e-12;
    const double inv = 1.0/n;
    for (int e = t; e < EMB; e += 256) {
        double v = pre[e]*inv;
        P64[(size_t)b*EMB + e] = v;
        Pb[(size_t)b*EMB + e] = f2bf((float)v);
    }
}

// ---------------- corpus prep: inverse norms (fp64) + bf16 conversion ----------------
__global__ __launch_bounds__(256) void corpus_prep(
    const float* __restrict__ corpus, unsigned short* __restrict__ Cb,
    float* __restrict__ inv32, double* __restrict__ inv64)
{
    const int t = threadIdx.x;
    const int row = blockIdx.x*4 + (t >> 6);
    const int lane = t & 63;
    const float* rp = corpus + (size_t)row*EMB + lane*8;
    const float4 v0 = *reinterpret_cast<const float4*>(rp);
    const float4 v1 = *reinterpret_cast<const float4*>(rp + 4);
    double ss = (double)v0.x*v0.x + (double)v0.y*v0.y + (double)v0.z*v0.z + (double)v0.w*v0.w
              + (double)v1.x*v1.x + (double)v1.y*v1.y + (double)v1.z*v1.z + (double)v1.w*v1.w;
#pragma unroll
    for (int off = 32; off >= 1; off >>= 1) ss += __shfl_xor(ss, off, 64);
    uint4 pk;
    pk.x = (uint32_t)f2bf(v0.x) | ((uint32_t)f2bf(v0.y) << 16);
    pk.y = (uint32_t)f2bf(v0.z) | ((uint32_t)f2bf(v0.w) << 16);
    pk.z = (uint32_t)f2bf(v1.x) | ((uint32_t)f2bf(v1.y) << 16);
    pk.w = (uint32_t)f2bf(v1.z) | ((uint32_t)f2bf(v1.w) << 16);
    *reinterpret_cast<uint4*>(Cb + (size_t)row*EMB + lane*8) = pk;
    if (lane == 0) {
        double n = sqrt(ss); if (n < 1e-12) n = 1e-12;
        double iv = 1.0/n;
        inv64[row] = iv;
        inv32[row] = (float)iv;
    }
}

// ---------------- weight pad+convert: fp32 [N,K] -> bf16 [N,KP] (zero pad) ----------------
__global__ __launch_bounds__(256) void pad_w(
    const float* __restrict__ W, unsigned short* __restrict__ dst, int K, int KP)
{
    const int row = blockIdx.x, t = threadIdx.x;
    for (int k = t; k < KP; k += 256)
        dst[(size_t)row*KP + k] = (k < K) ? f2bf(W[(size_t)row*K + k]) : (unsigned short)0;
}

// ---------------- phase 1: bf16 MFMA similarity scan + per-range top-8 ----------------
// block: 128 patients x one range (2048 docs), 4 waves, each wave 64p x 64d per tile.
// K-chunk = 128 per staging round (4 rounds per tile). Selection scratch overlays stage[0].
__global__ __launch_bounds__(256, 2) void mfma_scan(
    const unsigned short* __restrict__ Pb, const unsigned short* __restrict__ Cb,
    const float* __restrict__ inv32, float* __restrict__ cand_s, int* __restrict__ cand_i)
{
    // stage[0]=A (32 sets x 1KB), stage[1]=B. set = 64 lanes * 16B.
    __shared__ unsigned short stage[2][32*512];     // 64 KB
    __shared__ float ivb[DTILE];
    float* scs  = (float*)&stage[0][0];             // selection overlay (17.4 KB used)
    float* mb_s = scs;                              // merge overlay: [128][2][8]
    int*   mb_i = (int*)(scs + 2048);

    const int t = threadIdx.x;
    const int w = t >> 6, l = t & 63;
    const int lo = l & 15, q = l >> 4;
    const int pg = blockIdx.x;              // 0..7
    const int rg = blockIdx.y;              // 0..97
    const int pbase = pg*128;
    const int wp = (w >> 1)*64, wd = (w & 1)*64;
    const int isB = (w >> 1);               // waves 0,1 stage A; waves 2,3 stage B
    const int setbase = (w & 1)*16;

    float bs8[8]; int bi8[8];
#pragma unroll
    for (int k = 0; k < 8; ++k) { bs8[k] = -INFINITY; bi8[k] = 0; }

    for (int tile = 0; tile < RTILES; ++tile) {
        const int dt0 = rg*DRANGE + tile*DTILE;

        f32x4 acc[4][4];
#pragma unroll
        for (int i = 0; i < 4; ++i)
#pragma unroll
            for (int j = 0; j < 4; ++j) acc[i][j] = (f32x4){0.f, 0.f, 0.f, 0.f};

        for (int r = 0; r < 4; ++r) {
            __syncthreads();                          // stage free (prev consume/selection done)
            if (r == 0 && t < DTILE) { int d = dt0 + t; ivb[t] = inv32[d < NDOCS ? d : 0]; }
            const int kb = r*128;
#pragma unroll
            for (int n = 0; n < 16; ++n) {
                const int s  = setbase + n;           // 0..31
                const int rb = s & 7, ks = s >> 3;
                const int k  = kb + ks*32 + q*8;
                if (!isB) {
                    const unsigned short* gp = Pb + (size_t)(pbase + 16*rb + lo)*EMB + k;
                    load_lds16(gp, &stage[0][s*512 + l*8]);
                } else {
                    int row = dt0 + 16*rb + lo; if (row >= NDOCS) row = NDOCS - 1;
                    const unsigned short* gp = Cb + (size_t)row*EMB + k;
                    load_lds16(gp, &stage[1][s*512 + l*8]);
                }
            }
            __syncthreads();                          // stage ready
#pragma unroll
            for (int ks = 0; ks < 4; ++ks) {
                bf16x8 af[4], bfr[4];
#pragma unroll
                for (int i = 0; i < 4; ++i)
                    af[i] = *reinterpret_cast<const bf16x8*>(&stage[0][(ks*8 + (w>>1)*4 + i)*512 + l*8]);
#pragma unroll
                for (int j = 0; j < 4; ++j)
                    bfr[j] = *reinterpret_cast<const bf16x8*>(&stage[1][(ks*8 + (w&1)*4 + j)*512 + l*8]);
#pragma unroll
                for (int i = 0; i < 4; ++i)
#pragma unroll
                    for (int j = 0; j < 4; ++j)
                        acc[i][j] = __builtin_amdgcn_mfma_f32_16x16x32_bf16(af[i], bfr[j], acc[i][j], 0, 0, 0);
            }
        }
        __syncthreads();                              // all consume done; stage[0] free for scs

        // ---- selection via per-wave LDS transpose (overlay on stage[0]) ----
        float* sw = scs + w*1088;                     // 64*17 floats per wave
#pragma unroll
        for (int j = 0; j < 4; ++j) {
#pragma unroll
            for (int i = 0; i < 4; ++i)
#pragma unroll
                for (int rr = 0; rr < 4; ++rr)
                    sw[(16*i + 4*q + rr)*17 + lo] = acc[i][j][rr];
#pragma unroll
            for (int i = 0; i < 16; ++i) {
                const int d = dt0 + wd + 16*j + i;
                const float s = sw[l*17 + i] * ivb[wd + 16*j + i];
                if (d < NDOCS && s > bs8[7]) {
#pragma unroll
                    for (int k = 7; k >= 1; --k) {
                        const bool ck = s > bs8[k];
                        const bool cp = s > bs8[k-1];
                        bs8[k] = ck ? (cp ? bs8[k-1] : s) : bs8[k];
                        bi8[k] = ck ? (cp ? bi8[k-1] : d) : bi8[k];
                    }
                    if (s > bs8[0]) { bs8[0] = s; bi8[0] = d; }
                }
            }
        }
    }

    // ---- merge the two 64-doc halves per patient ----
    __syncthreads();
    {
        const int pl = wp + l, half = w & 1;
#pragma unroll
        for (int k = 0; k < 8; ++k) {
            mb_s[(pl*2 + half)*8 + k] = bs8[k];
            mb_i[(pl*2 + half)*8 + k] = bi8[k];
        }
    }
    __syncthreads();
    if (t < 128) {
        float os8[8]; int oi8[8];
#pragma unroll
        for (int k = 0; k < 8; ++k) { os8[k] = -INFINITY; oi8[k] = 0x7fffffff; }
        for (int u = 0; u < 16; ++u) {
            const float s = mb_s[t*16 + u]; const int idx = mb_i[t*16 + u];
            const bool b7 = (s > os8[7]) || (s == os8[7] && idx < oi8[7]);
            if (b7) {
#pragma unroll
                for (int k = 7; k >= 1; --k) {
                    const bool ck = (s > os8[k])   || (s == os8[k]   && idx < oi8[k]);
                    const bool cp = (s > os8[k-1]) || (s == os8[k-1] && idx < oi8[k-1]);
                    os8[k] = ck ? (cp ? os8[k-1] : s)   : os8[k];
                    oi8[k] = ck ? (cp ? oi8[k-1] : idx) : oi8[k];
                }
                const bool c0 = (s > os8[0]) || (s == os8[0] && idx < oi8[0]);
                if (c0) { os8[0] = s; oi8[0] = idx; }
            }
        }
        const size_t base = (size_t)(pbase + t)*NCAND + rg*8;
#pragma unroll
        for (int k = 0; k < 8; ++k) { cand_s[base + k] = os8[k]; cand_i[base + k] = oi8[k]; }
    }
}

// ---------------- bf16 MFMA GEMM: C(bf16) = relu(X @ W^T + bias) ----------------
// X [M, ld] bf16, W [N, ld] bf16 (K zero-padded), C [M, ldc] bf16.
// block tile 128x128, 4 waves, K-chunk 128 per staging round.
__global__ __launch_bounds__(256, 2) void gemm_bf16(
    const unsigned short* __restrict__ X, const unsigned short* __restrict__ W,
    const float* __restrict__ bias, unsigned short* __restrict__ C,
    int ld, int rounds, int ldc)
{
    __shared__ unsigned short stage[2][32*512];
    const int t = threadIdx.x;
    const int w = t >> 6, l = t & 63;
    const int lo = l & 15, q = l >> 4;
    const int n0 = blockIdx.x*128, m0 = blockIdx.y*128;
    const int wp = (w >> 1)*64, wd = (w & 1)*64;
    const int isB = (w >> 1);
    const int setbase = (w & 1)*16;

    f32x4 acc[4][4];
#pragma unroll
    for (int i = 0; i < 4; ++i)
#pragma unroll
        for (int j = 0; j < 4; ++j) acc[i][j] = (f32x4){0.f, 0.f, 0.f, 0.f};

    for (int r = 0; r < rounds; ++r) {
        __syncthreads();
        const int kb = r*128;
#pragma unroll
        for (int n = 0; n < 16; ++n) {
            const int s  = setbase + n;
            const int rb = s & 7, ks = s >> 3;
            const int k  = kb + ks*32 + q*8;
            if (!isB) {
                const unsigned short* gp = X + (size_t)(m0 + 16*rb + lo)*ld + k;
                load_lds16(gp, &stage[0][s*512 + l*8]);
            } else {
                const unsigned short* gp = W + (size_t)(n0 + 16*rb + lo)*ld + k;
                load_lds16(gp, &stage[1][s*512 + l*8]);
            }
        }
        __syncthreads();
#pragma unroll
        for (int ks = 0; ks < 4; ++ks) {
            bf16x8 af[4], bfr[4];
#pragma unroll
            for (int i = 0; i < 4; ++i)
                af[i] = *reinterpret_cast<const bf16x8*>(&stage[0][(ks*8 + (w>>1)*4 + i)*512 + l*8]);
#pragma unroll
            for (int j = 0; j < 4; ++j)
                bfr[j] = *reinterpret_cast<const bf16x8*>(&stage[1][(ks*8 + (w&1)*4 + j)*512 + l*8]);
#pragma unroll
            for (int i = 0; i < 4; ++i)
#pragma unroll
                for (int j = 0; j < 4; ++j)
                    acc[i][j] = __builtin_amdgcn_mfma_f32_16x16x32_bf16(af[i], bfr[j], acc[i][j], 0, 0, 0);
        }
    }
#pragma unroll
    for (int j = 0; j < 4; ++j) {
        const int n = n0 + wd + 16*j + lo;
        const float bn = bias[n];
#pragma unroll
        for (int i = 0; i < 4; ++i)
#pragma unroll
            for (int rr = 0; rr < 4; ++rr) {
                const int m = m0 + wp + 16*i + 4*q + rr;
                float v = acc[i][j][rr] + bn;
                v = fmaxf(v, 0.f);
                C[(size_t)m*ldc + n] = f2bf(v);
            }
    }
}

// ---------------- phase 2: merge candidates, fp64 rescore, exact top-8 ----------------
__global__ __launch_bounds__(256) void select_rescore(
    const float* __restrict__ cand_s, const int* __restrict__ cand_i,
    const double* __restrict__ P64, const float* __restrict__ corpus,
    const double* __restrict__ inv64, float* __restrict__ out, int* __restrict__ topk)
{
    __shared__ float  ls[NCAND];
    __shared__ int    li[NCAND];
    __shared__ int    chosen[RESCORE];
    __shared__ double rs[RESCORE];
    __shared__ float  red_s[4];
    __shared__ int    red_i[4];
    __shared__ int    red_j[4];
    const int t = threadIdx.x, p = blockIdx.x;
    const int lane = t & 63, wid = t >> 6;

    for (int j = t; j < NCAND; j += 256) {
        ls[j] = cand_s[(size_t)p*NCAND + j];
        li[j] = cand_i[(size_t)p*NCAND + j];
    }
    __syncthreads();

    for (int round = 0; round < RESCORE; ++round) {
        float bs = -INFINITY; int bi = 0x7fffffff, bj = -1;
        for (int j = t; j < NCAND; j += 256) {
            const float s = ls[j]; const int i = li[j];
            if (s > bs || (s == bs && i < bi)) { bs = s; bi = i; bj = j; }
        }
#pragma unroll
        for (int off = 32; off >= 1; off >>= 1) {
            const float os = __shfl_xor(bs, off, 64);
            const int   oi = __shfl_xor(bi, off, 64);
            const int   oj = __shfl_xor(bj, off, 64);
            if (os > bs || (os == bs && oi < bi)) { bs = os; bi = oi; bj = oj; }
        }
        if (lane == 0) { red_s[wid] = bs; red_i[wid] = bi; red_j[wid] = bj; }
        __syncthreads();
        if (t == 0) {
            float s0 = red_s[0]; int i0 = red_i[0], j0 = red_j[0];
            for (int w2 = 1; w2 < 4; ++w2)
                if (red_s[w2] > s0 || (red_s[w2] == s0 && red_i[w2] < i0)) {
                    s0 = red_s[w2]; i0 = red_i[w2]; j0 = red_j[w2];
                }
            chosen[round] = i0;
            ls[j0] = -INFINITY;
        }
        __syncthreads();
    }

    for (int c = wid; c < RESCORE; c += 4) {
        const int doc = chosen[c];
        double s = 0.0;
#pragma unroll
        for (int m = 0; m < 8; ++m)
            s += P64[(size_t)p*EMB + lane + 64*m] * (double)corpus[(size_t)doc*EMB + lane + 64*m];
#pragma unroll
        for (int off = 32; off >= 1; off >>= 1) s += __shfl_xor(s, off, 64);
        if (lane == 0) rs[c] = s * inv64[doc];
    }
    __syncthreads();

    if (t == 0) {
        for (int k = 0; k < TOPKN; ++k) {
            double bsd = -1e300; int bid = 0x7fffffff, bjd = -1;
            for (int j = 0; j < RESCORE; ++j) {
                const double s = rs[j]; const int i = chosen[j];
                if (s > bsd || (s == bsd && i < bid)) { bsd = s; bid = i; bjd = j; }
            }
            out[OUT_SCORES + p*TOPKN + k] = (float)bsd;
            out[OUT_IDX    + p*TOPKN + k] = (float)bid;
            topk[p*TOPKN + k] = bid;
            rs[bjd] = -1e300;
        }
    }
}

// ---------------- build fs_in (bf16) = [instruments | retrieved_flat | 0-pad] ----------------
__global__ __launch_bounds__(256) void build_fs(
    const float* __restrict__ instr, const unsigned short* __restrict__ Cb,
    const int* __restrict__ topk, unsigned short* __restrict__ fsb)
{
    const int p = blockIdx.x, t = threadIdx.x;
    for (int j = t; j < KP_FS; j += 256) {
        unsigned short v = 0;
        if (j < 20) v = f2bf(instr[p*20 + j]);
        else if (j < 20 + TOPKN*EMB) {
            const int k = j - 20;
            const int doc = topk[p*TOPKN + (k >> 9)];
            v = Cb[(size_t)doc*EMB + (k & 511)];
        }
        fsb[(size_t)p*KP_FS + j] = v;
    }
}

// ---------------- build ss_in (bf16) = [pt | confounders | retrieved_flat | 0-pad] ----------------
__global__ __launch_bounds__(256) void build_ss(
    const float* __restrict__ pt, const float* __restrict__ conf,
    const unsigned short* __restrict__ Cb, const int* __restrict__ topk,
    unsigned short* __restrict__ ssb)
{
    const int p = blockIdx.x, t = threadIdx.x;
    for (int j = t; j < KP_FS; j += 256) {
        unsigned short v = 0;
        if (j < 2) v = f2bf(pt[p*2 + j]);
        else if (j < 66) v = f2bf(conf[p*CONFN + (j - 2)]);
        else if (j < 66 + TOPKN*EMB) {
            const int k = j - 66;
            const int doc = topk[p*TOPKN + (k >> 9)];
            v = Cb[(size_t)doc*EMB + (k & 511)];
        }
        ssb[(size_t)p*KP_FS + j] = v;
    }
}

// ---------------- predicted treatment: pt = h1 @ W1b^T + b1b (h1 bf16) ----------------
__global__ __launch_bounds__(256) void pt_kernel(
    const unsigned short* __restrict__ h1, const float* __restrict__ W1b,
    const float* __restrict__ b1b, float* __restrict__ pt, float* __restrict__ out)
{
    const int t = threadIdx.x;
    const int w = blockIdx.x*4 + (t >> 6);
    const int lane = t & 63;
    const int b = w >> 1, tr = w & 1;
    float s = 0.f;
#pragma unroll
    for (int m = 0; m < 16; ++m)
        s += bf2f(h1[(size_t)b*HID + lane + 64*m]) * W1b[tr*HID + lane + 64*m];
#pragma unroll
    for (int off = 32; off >= 1; off >>= 1) s += __shfl_xor(s, off, 64);
    if (lane == 0) {
        const float v = s + b1b[tr];
        pt[b*2 + tr] = v;
        out[OUT_PT + b*2 + tr] = v;
    }
}

// ---------------- outcome = h3 @ W2c^T + b2c (h3 bf16) ----------------
__global__ __launch_bounds__(256) void outcome_kernel(
    const unsigned short* __restrict__ h3, const float* __restrict__ W2c,
    const float* __restrict__ b2c, float* __restrict__ out)
{
    const int t = threadIdx.x;
    const int b = blockIdx.x*4 + (t >> 6);
    const int lane = t & 63;
    float s = 0.f;
#pragma unroll
    for (int m = 0; m < 8; ++m)
        s += bf2f(h3[(size_t)b*512 + lane + 64*m]) * W2c[lane + 64*m];
#pragma unroll
    for (int off = 32; off >= 1; off >>= 1) s += __shfl_xor(s, off, 64);
    if (lane == 0) out[b] = s + b2c[0];
}

__global__ __launch_bounds__(256) void iv_kernel(
    const float* __restrict__ instr, const float* __restrict__ W_iv,
    const float* __restrict__ b_iv, float* __restrict__ out)
{
    const int gid = blockIdx.x*256 + threadIdx.x;
    const int b = gid >> 1, tr = gid & 1;
    float s = b_iv[tr];
#pragma unroll
    for (int i = 0; i < 20; ++i) s += instr[b*20 + i] * W_iv[tr*20 + i];
    out[OUT_IV + gid] = s;
}

extern "C" void kernel_launch(void* const* d_in, const int* in_sizes, int n_in,
                              void* d_out, int out_size, void* d_ws, size_t ws_size,
                              hipStream_t stream)
{
    (void)in_sizes; (void)n_in; (void)out_size; (void)ws_size;
    const float* patient = (const float*)d_in[0];
    const float* conf    = (const float*)d_in[1];
    const float* instr   = (const float*)d_in[2];
    const float* corpus  = (const float*)d_in[3];
    const float* W_enc   = (const float*)d_in[4];
    const float* b_enc   = (const float*)d_in[5];
    const float* W1a     = (const float*)d_in[6];
    const float* b1a     = (const float*)d_in[7];
    const float* W1b     = (const float*)d_in[8];
    const float* b1b     = (const float*)d_in[9];
    const float* W2a     = (const float*)d_in[10];
    const float* b2a     = (const float*)d_in[11];
    const float* W2b     = (const float*)d_in[12];
    const float* b2b     = (const float*)d_in[13];
    const float* W2c     = (const float*)d_in[14];
    const float* b2c     = (const float*)d_in[15];
    const float* W_iv    = (const float*)d_in[16];
    const float* b_iv    = (const float*)d_in[17];
    float* out = (float*)d_out;
    char* ws = (char*)d_ws;

    unsigned short* Pb   = (unsigned short*)(ws + OFF_PB);
    double* P64          = (double*)(ws + OFF_P64);
    unsigned short* Cb   = (unsigned short*)(ws + OFF_CB);
    float*  inv32        = (float*) (ws + OFF_INV32);
    double* inv64        = (double*)(ws + OFF_INV64);
    float*  candS        = (float*) (ws + OFF_CS);
    int*    candI        = (int*)   (ws + OFF_CI);
    int*    topk         = (int*)   (ws + OFF_TOPK);
    unsigned short* fsb  = (unsigned short*)(ws + OFF_FSB);
    unsigned short* ssb  = (unsigned short*)(ws + OFF_SSB);
    unsigned short* h1b  = (unsigned short*)(ws + OFF_H1);
    unsigned short* h2b  = (unsigned short*)(ws + OFF_H2);
    unsigned short* h3b  = (unsigned short*)(ws + OFF_H3);
    float*  ptb          = (float*) (ws + OFF_PT);
    unsigned short* W1ab = (unsigned short*)(ws + OFF_W1);
    unsigned short* W2ab = (unsigned short*)(ws + OFF_W2A);
    unsigned short* W2bb = (unsigned short*)(ws + OFF_W2B);

    encode_kernel<<<BATCH, 256, 0, stream>>>(patient, W_enc, b_enc, Pb, P64);
    corpus_prep<<<NDOCS/4, 256, 0, stream>>>(corpus, Cb, inv32, inv64);
    pad_w<<<HID, 256, 0, stream>>>(W1a, W1ab, 4116, KP_FS);
    pad_w<<<HID, 256, 0, stream>>>(W2a, W2ab, 4162, KP_FS);
    pad_w<<<512, 256, 0, stream>>>(W2b, W2bb, 1024, 1024);
    mfma_scan<<<dim3(NPG, NRANGE), 256, 0, stream>>>(Pb, Cb, inv32, candS, candI);
    select_rescore<<<BATCH, 256, 0, stream>>>(candS, candI, P64, corpus, inv64, out, topk);
    build_fs<<<BATCH, 256, 0, stream>>>(instr, Cb, topk, fsb);
    gemm_bf16<<<dim3(8, 8), 256, 0, stream>>>(fsb, W1ab, b1a, h1b, KP_FS, R_FS, HID);
    pt_kernel<<<512, 256, 0, stream>>>(h1b, W1b, b1b, ptb, out);
    build_ss<<<BATCH, 256, 0, stream>>>(ptb, conf, Cb, topk, ssb);
    gemm_bf16<<<dim3(8, 8), 256, 0, stream>>>(ssb, W2ab, b2a, h2b, KP_FS, R_FS, HID);
    gemm_bf16<<<dim3(4, 8), 256, 0, stream>>>(h2b, W2bb, b2b, h3b, HID, 8, 512);
    outcome_kernel<<<BATCH/4, 256, 0, stream>>>(h3b, W2c, b2c, out);
    iv_kernel<<<8, 256, 0, stream>>>(instr, W_iv, b_iv, out);
}